// Round 1
// baseline (249.103 us; speedup 1.0000x reference)
//
#include <hip/hip_runtime.h>
#include <stdint.h>

#define D_MODEL 1024
#define NHEAD 16
#define DK 64
#define BATCH 2
#define SEQ 2048
#define MROWS (BATCH * SEQ) /* 4096 */

typedef __attribute__((ext_vector_type(8))) __bf16 bf16x8;
typedef __attribute__((ext_vector_type(4))) float f32x4;

__device__ __forceinline__ f32x4 f4zero() {
  f32x4 z = {0.f, 0.f, 0.f, 0.f};
  return z;
}

__device__ __forceinline__ f32x4 mfma_bf16(bf16x8 a, bf16x8 b, f32x4 c) {
  return __builtin_amdgcn_mfma_f32_16x16x32_bf16(a, b, c, 0, 0, 0);
}

// async global->LDS, 16B per lane; LDS dest = uniform base + lane*16
__device__ __forceinline__ void gload_lds16(const void* g, void* l) {
  __builtin_amdgcn_global_load_lds(
      (const __attribute__((address_space(1))) unsigned int*)g,
      (__attribute__((address_space(3))) unsigned int*)l, 16, 0, 0);
}

__device__ __forceinline__ unsigned short f2b(float x) {  // RNE fp32->bf16
  unsigned int u = __float_as_uint(x);
  u += 0x7fffu + ((u >> 16) & 1u);
  return (unsigned short)(u >> 16);
}
__device__ __forceinline__ float b2f(unsigned short u) {
  return __uint_as_float(((unsigned int)u) << 16);
}

// ---------------- fp32 -> bf16 convert (and hi/lo split) ----------------
__global__ void cvt_bf16_kernel(const float* __restrict__ in,
                                unsigned short* __restrict__ out, int n4) {
  int i = blockIdx.x * blockDim.x + threadIdx.x;
  if (i >= n4) return;
  float4 v = ((const float4*)in)[i];
  ushort4 o;
  o.x = f2b(v.x); o.y = f2b(v.y); o.z = f2b(v.z); o.w = f2b(v.w);
  ((ushort4*)out)[i] = o;
}

__global__ void split_bf16_kernel(const float* __restrict__ in,
                                  unsigned short* __restrict__ hi,
                                  unsigned short* __restrict__ lo, int n4) {
  int i = blockIdx.x * blockDim.x + threadIdx.x;
  if (i >= n4) return;
  float4 v = ((const float4*)in)[i];
  ushort4 h, l;
  h.x = f2b(v.x); h.y = f2b(v.y); h.z = f2b(v.z); h.w = f2b(v.w);
  l.x = f2b(v.x - b2f(h.x));
  l.y = f2b(v.y - b2f(h.y));
  l.z = f2b(v.z - b2f(h.z));
  l.w = f2b(v.w - b2f(h.w));
  ((ushort4*)hi)[i] = h;
  ((ushort4*)lo)[i] = l;
}

// ---------------- GEMM: Y[M,N] = A[M,K] * W[N,K]^T + bias ----------------
// 128x128 tile, BK=32, 4 waves, each wave 64x64 (4x4 fragments of 16x16x32).
// LDS chunk-XOR swizzle: logical 16B-chunk u of row r stored at chunk u^(r&3).
// SPLIT: 3-term hi/lo bf16 product (fp32-class accuracy).
// EPI==0: write bf16 to outb ; EPI==1: write fp32 (+bias) to outf.
template <int SPLIT, int EPI>
__global__ __launch_bounds__(256, 2) void gemm_kernel(
    const unsigned short* __restrict__ A, const unsigned short* __restrict__ Al,
    const unsigned short* __restrict__ Bm, const unsigned short* __restrict__ Bl,
    const float* __restrict__ bias, unsigned short* __restrict__ outb,
    float* __restrict__ outf, int M, int N, int K) {
  __shared__ __attribute__((aligned(16))) unsigned short sA[128 * 32];
  __shared__ __attribute__((aligned(16))) unsigned short sB[128 * 32];
  __shared__ __attribute__((aligned(16))) unsigned short sAl[SPLIT ? 128 * 32 : 8];
  __shared__ __attribute__((aligned(16))) unsigned short sBl[SPLIT ? 128 * 32 : 8];

  const int tid = threadIdx.x;
  const int w = tid >> 6, l = tid & 63;
  const int nTilesN = N >> 7;
  const int bm = blockIdx.x / nTilesN, bn = blockIdx.x % nTilesN;
  const int rowBase = bm << 7, colBase = bn << 7;
  const int wm = w >> 1, wn = w & 1;
  const int g = l >> 4, c16 = l & 15;

  f32x4 acc[4][4];
#pragma unroll
  for (int i = 0; i < 4; i++)
#pragma unroll
    for (int j = 0; j < 4; j++) acc[i][j] = f4zero();

  const int rloc = l >> 2;                  // 16 rows per wave-call
  const int uch = (l & 3) ^ (rloc & 3);     // pre-swizzled source chunk

  for (int kk = 0; kk < K; kk += 32) {
    __syncthreads();
#pragma unroll
    for (int h = 0; h < 2; h++) {
      const int r0 = w * 16 + h * 64;
      const size_t arow = (size_t)(rowBase + r0 + rloc);
      const size_t brow = (size_t)(colBase + r0 + rloc);
      gload_lds16(A + arow * K + kk + uch * 8, &sA[r0 * 32]);
      gload_lds16(Bm + brow * K + kk + uch * 8, &sB[r0 * 32]);
      if (SPLIT) {
        gload_lds16(Al + arow * K + kk + uch * 8, &sAl[r0 * 32]);
        gload_lds16(Bl + brow * K + kk + uch * 8, &sBl[r0 * 32]);
      }
    }
    __syncthreads();

    bf16x8 af[4], bf[4], afl[4], bfl[4];
#pragma unroll
    for (int mt = 0; mt < 4; mt++) {
      const int r = wm * 64 + mt * 16 + c16;
      const int c = g ^ (r & 3);
      af[mt] = *(const bf16x8*)&sA[r * 32 + c * 8];
      if (SPLIT) afl[mt] = *(const bf16x8*)&sAl[r * 32 + c * 8];
    }
#pragma unroll
    for (int nt = 0; nt < 4; nt++) {
      const int r = wn * 64 + nt * 16 + c16;
      const int c = g ^ (r & 3);
      bf[nt] = *(const bf16x8*)&sB[r * 32 + c * 8];
      if (SPLIT) bfl[nt] = *(const bf16x8*)&sBl[r * 32 + c * 8];
    }
#pragma unroll
    for (int mt = 0; mt < 4; mt++)
#pragma unroll
      for (int nt = 0; nt < 4; nt++) {
        acc[mt][nt] = mfma_bf16(af[mt], bf[nt], acc[mt][nt]);
        if (SPLIT) {
          acc[mt][nt] = mfma_bf16(af[mt], bfl[nt], acc[mt][nt]);
          acc[mt][nt] = mfma_bf16(afl[mt], bf[nt], acc[mt][nt]);
        }
      }
  }

  // epilogue: C/D layout row = g*4+i, col = c16
#pragma unroll
  for (int mt = 0; mt < 4; mt++)
#pragma unroll
    for (int nt = 0; nt < 4; nt++) {
      const int col = colBase + wn * 64 + nt * 16 + c16;
      const float bv = bias[col];
#pragma unroll
      for (int i = 0; i < 4; i++) {
        const int row = rowBase + wm * 64 + mt * 16 + g * 4 + i;
        const float v = acc[mt][nt][i] + bv;
        if (EPI == 0)
          outb[(size_t)row * N + col] = f2b(v);
        else
          outf[(size_t)row * N + col] = v;
      }
    }
}

// ---------------- V transpose: Vh[B,S,D] -> Vt[(b*16+h)*64+d][S] ----------
__global__ void transpose_v_kernel(const unsigned short* __restrict__ Vh,
                                   unsigned short* __restrict__ Vt) {
  const int t = threadIdx.x;
  const int d = t & 63, grp = t >> 6;
  const int s0 = blockIdx.x * 64 + grp * 16;
  const int bh = blockIdx.y;
  const int b = bh >> 4, h = bh & 15;
  unsigned short vals[16];
#pragma unroll
  for (int j = 0; j < 16; j++)
    vals[j] = Vh[(size_t)(b * SEQ + s0 + j) * D_MODEL + h * DK + d];
  unsigned short* dst = &Vt[(size_t)(bh * DK + d) * SEQ + s0];
  ((uint4*)dst)[0] = ((uint4*)vals)[0];
  ((uint4*)dst)[1] = ((uint4*)vals)[1];
}

// ---------------- flash attention ----------------
// grid (16, 32): x = 128-row q block, y = (b*16+h). 4 waves * 32 q-rows.
// Swapped QK^T: st = mfma(Kfrag, Qfrag) -> S^T[key][q]; softmax reduce over
// keys = in-lane 8 + shfl_xor 16,32. P staged per-wave in padded LDS to
// re-layout into A-frags. V consumed from pre-transposed Vt.
__global__ __launch_bounds__(256, 2) void attn_kernel(
    const unsigned short* __restrict__ Qh, const unsigned short* __restrict__ Kh,
    const unsigned short* __restrict__ Vt, unsigned short* __restrict__ Xh,
    unsigned short* __restrict__ Xl) {
  __shared__ __attribute__((aligned(16))) unsigned short sK[32 * 64];  // [key][d]
  __shared__ __attribute__((aligned(16))) unsigned short sV[64 * 32];  // [d][key]
  __shared__ __attribute__((aligned(16))) unsigned short sP[4][32 * 40];

  const int tid = threadIdx.x, w = tid >> 6, l = tid & 63;
  const int bh = blockIdx.y;
  const int b = bh >> 4, h = bh & 15;
  const int q0 = blockIdx.x * 128 + w * 32;
  const int g = l >> 4, c16 = l & 15;

  // hoist Q B-frags: b[i] = Q[q=c16][dd = f*32 + g*8 + i]
  bf16x8 qf[2][2];
#pragma unroll
  for (int qt = 0; qt < 2; qt++)
#pragma unroll
    for (int f = 0; f < 2; f++) {
      const size_t a =
          (size_t)(b * SEQ + q0 + qt * 16 + c16) * D_MODEL + h * DK + f * 32 + g * 8;
      qf[qt][f] = *(const bf16x8*)&Qh[a];
    }

  f32x4 acc[2][4];
#pragma unroll
  for (int mt = 0; mt < 2; mt++)
#pragma unroll
    for (int dt = 0; dt < 4; dt++) acc[mt][dt] = f4zero();
  float mrun[2] = {-1e30f, -1e30f};
  float lrun[2] = {0.f, 0.f};

  const int krow = l >> 3;                 // K: 8 rows / wave-call
  const int kch = (l & 7) ^ (krow & 7);
  const int vrow = l >> 2;                 // V: 16 rows / wave-call
  const int vch = (l & 3) ^ (vrow & 3);

  for (int kv0 = 0; kv0 < SEQ; kv0 += 32) {
    __syncthreads();
    {
      const size_t krg = (size_t)(b * SEQ + kv0 + w * 8 + krow);
      gload_lds16(Kh + krg * D_MODEL + h * DK + kch * 8, &sK[(w * 8) * 64]);
      const size_t vrg = (size_t)(bh * DK + w * 16 + vrow);
      gload_lds16(Vt + vrg * SEQ + kv0 + vch * 8, &sV[(w * 16) * 32]);
    }
    __syncthreads();

    // S^T = K * Q^T
    bf16x8 kf[2][2];
#pragma unroll
    for (int kt = 0; kt < 2; kt++)
#pragma unroll
      for (int f = 0; f < 2; f++) {
        const int key = kt * 16 + c16;
        const int ch = (f * 4 + g) ^ (key & 7);
        kf[kt][f] = *(const bf16x8*)&sK[key * 64 + ch * 8];
      }
    f32x4 st[2][2];
#pragma unroll
    for (int kt = 0; kt < 2; kt++)
#pragma unroll
      for (int qt = 0; qt < 2; qt++) {
        f32x4 s = f4zero();
        s = mfma_bf16(kf[kt][0], qf[qt][0], s);
        s = mfma_bf16(kf[kt][1], qf[qt][1], s);
        st[kt][qt] = s;
      }

    float alpha[2];
#pragma unroll
    for (int qt = 0; qt < 2; qt++) {
      float mx = -1e30f;
#pragma unroll
      for (int kt = 0; kt < 2; kt++)
#pragma unroll
        for (int i = 0; i < 4; i++) mx = fmaxf(mx, st[kt][qt][i]);
      mx = fmaxf(mx, __shfl_xor(mx, 16));
      mx = fmaxf(mx, __shfl_xor(mx, 32));
      mx *= 0.125f;
      const float mnew = fmaxf(mrun[qt], mx);
      alpha[qt] = __expf(mrun[qt] - mnew);
      float ps = 0.f;
#pragma unroll
      for (int kt = 0; kt < 2; kt++)
#pragma unroll
        for (int i = 0; i < 4; i++) {
          const float p = __expf(st[kt][qt][i] * 0.125f - mnew);
          ps += p;
          sP[w][(qt * 16 + c16) * 40 + kt * 16 + g * 4 + i] = f2b(p);
        }
      ps += __shfl_xor(ps, 16);
      ps += __shfl_xor(ps, 32);
      lrun[qt] = lrun[qt] * alpha[qt] + ps;
      mrun[qt] = mnew;
    }

    // rescale O by alpha (broadcast column-layout alpha to row-layout)
#pragma unroll
    for (int mt = 0; mt < 2; mt++)
#pragma unroll
      for (int i = 0; i < 4; i++) {
        const float a = __shfl(alpha[mt], g * 4 + i);
#pragma unroll
        for (int dt = 0; dt < 4; dt++) acc[mt][dt][i] *= a;
      }

    __syncthreads();  // P visibility (cross-lane within wave)

    bf16x8 pf[2], vf[4];
#pragma unroll
    for (int mt = 0; mt < 2; mt++)
      pf[mt] = *(const bf16x8*)&sP[w][(mt * 16 + c16) * 40 + g * 8];
#pragma unroll
    for (int dt = 0; dt < 4; dt++) {
      const int d = dt * 16 + c16;
      const int ch = g ^ (d & 3);
      vf[dt] = *(const bf16x8*)&sV[d * 32 + ch * 8];
    }
#pragma unroll
    for (int mt = 0; mt < 2; mt++)
#pragma unroll
      for (int dt = 0; dt < 4; dt++)
        acc[mt][dt] = mfma_bf16(pf[mt], vf[dt], acc[mt][dt]);
  }

  // finalize: divide by l, split to hi/lo bf16 for the output GEMM
#pragma unroll
  for (int mt = 0; mt < 2; mt++)
#pragma unroll
    for (int i = 0; i < 4; i++) {
      const float linv = 1.f / __shfl(lrun[mt], g * 4 + i);
      const int row = b * SEQ + q0 + mt * 16 + g * 4 + i;
#pragma unroll
      for (int dt = 0; dt < 4; dt++) {
        const int col = h * DK + dt * 16 + c16;
        const float x = acc[mt][dt][i] * linv;
        const unsigned short xh = f2b(x);
        const size_t a = (size_t)row * D_MODEL + col;
        Xh[a] = xh;
        Xl[a] = f2b(x - b2f(xh));
      }
    }
}

// ---------------- host ----------------
extern "C" void kernel_launch(void* const* d_in, const int* in_sizes, int n_in,
                              void* d_out, int out_size, void* d_ws, size_t ws_size,
                              hipStream_t stream) {
  (void)in_sizes; (void)n_in; (void)out_size; (void)ws_size;
  const float* q = (const float*)d_in[0];
  const float* k = (const float*)d_in[1];
  const float* v = (const float*)d_in[2];
  const float* w_q = (const float*)d_in[3];
  const float* b_q = (const float*)d_in[4];
  const float* w_k = (const float*)d_in[5];
  const float* b_k = (const float*)d_in[6];
  const float* w_v = (const float*)d_in[7];
  const float* b_v = (const float*)d_in[8];
  const float* w_o = (const float*)d_in[9];
  const float* b_o = (const float*)d_in[10];

  const size_t SZ_ACT = (size_t)MROWS * D_MODEL;  // elements
  const size_t SZ_W = (size_t)D_MODEL * D_MODEL;
  char* ws = (char*)d_ws;
  unsigned short* qb = (unsigned short*)(ws);                    // reused as Xh
  unsigned short* kb = (unsigned short*)(ws + 2 * SZ_ACT);       // reused as Xl
  unsigned short* vb = (unsigned short*)(ws + 4 * SZ_ACT);       // reused as Vt
  unsigned short* Qh = (unsigned short*)(ws + 6 * SZ_ACT);
  unsigned short* Kh = (unsigned short*)(ws + 8 * SZ_ACT);
  unsigned short* Vh = (unsigned short*)(ws + 10 * SZ_ACT);
  unsigned short* wqb = (unsigned short*)(ws + 12 * SZ_ACT);
  unsigned short* wkb = (unsigned short*)(ws + 12 * SZ_ACT + 2 * SZ_W);
  unsigned short* wvb = (unsigned short*)(ws + 12 * SZ_ACT + 4 * SZ_W);
  unsigned short* woh = (unsigned short*)(ws + 12 * SZ_ACT + 6 * SZ_W);
  unsigned short* wol = (unsigned short*)(ws + 12 * SZ_ACT + 8 * SZ_W);
  unsigned short* Xh = qb;
  unsigned short* Xl = kb;
  unsigned short* Vt = vb;

  const int actN4 = (int)(SZ_ACT / 4), wN4 = (int)(SZ_W / 4);
  cvt_bf16_kernel<<<actN4 / 256, 256, 0, stream>>>(q, qb, actN4);
  cvt_bf16_kernel<<<actN4 / 256, 256, 0, stream>>>(k, kb, actN4);
  cvt_bf16_kernel<<<actN4 / 256, 256, 0, stream>>>(v, vb, actN4);
  cvt_bf16_kernel<<<wN4 / 256, 256, 0, stream>>>(w_q, wqb, wN4);
  cvt_bf16_kernel<<<wN4 / 256, 256, 0, stream>>>(w_k, wkb, wN4);
  cvt_bf16_kernel<<<wN4 / 256, 256, 0, stream>>>(w_v, wvb, wN4);
  split_bf16_kernel<<<wN4 / 256, 256, 0, stream>>>(w_o, woh, wol, wN4);

  const int gemmGrid = (MROWS / 128) * (D_MODEL / 128);  // 256
  gemm_kernel<0, 0><<<gemmGrid, 256, 0, stream>>>(qb, nullptr, wqb, nullptr, b_q,
                                                  Qh, nullptr, MROWS, D_MODEL, D_MODEL);
  gemm_kernel<0, 0><<<gemmGrid, 256, 0, stream>>>(kb, nullptr, wkb, nullptr, b_k,
                                                  Kh, nullptr, MROWS, D_MODEL, D_MODEL);
  gemm_kernel<0, 0><<<gemmGrid, 256, 0, stream>>>(vb, nullptr, wvb, nullptr, b_v,
                                                  Vh, nullptr, MROWS, D_MODEL, D_MODEL);

  transpose_v_kernel<<<dim3(SEQ / 64, BATCH * NHEAD), 256, 0, stream>>>(Vh, Vt);

  attn_kernel<<<dim3(SEQ / 128, BATCH * NHEAD), 256, 0, stream>>>(Qh, Kh, Vt, Xh, Xl);

  gemm_kernel<1, 1><<<gemmGrid, 256, 0, stream>>>(Xh, Xl, woh, wol, b_o, nullptr,
                                                  (float*)d_out, MROWS, D_MODEL, D_MODEL);
}

// Round 3
// 166.713 us; speedup vs baseline: 1.4942x; 1.4942x over previous
//
#include <hip/hip_runtime.h>
#include <stdint.h>

#define D_MODEL 1024
#define NHEAD 16
#define DK 64
#define BATCH 2
#define SEQ 2048
#define MROWS (BATCH * SEQ) /* 4096 */
#define KVB 64
#define NIT (SEQ / KVB) /* 32 */

typedef __attribute__((ext_vector_type(8))) __bf16 bf16x8;
typedef __attribute__((ext_vector_type(2))) __bf16 bf16x2;
typedef __attribute__((ext_vector_type(4))) float f32x4;
typedef __attribute__((ext_vector_type(4))) unsigned int u32x4;

__device__ __forceinline__ f32x4 f4zero() {
  f32x4 z = {0.f, 0.f, 0.f, 0.f};
  return z;
}

__device__ __forceinline__ f32x4 mfma_bf16(bf16x8 a, bf16x8 b, f32x4 c) {
  return __builtin_amdgcn_mfma_f32_16x16x32_bf16(a, b, c, 0, 0, 0);
}

// async global->LDS, 16B per lane; LDS dest = wave-uniform base + lane*16
__device__ __forceinline__ void gload_lds16(const void* g, void* l) {
  __builtin_amdgcn_global_load_lds(
      (const __attribute__((address_space(1))) unsigned int*)g,
      (__attribute__((address_space(3))) unsigned int*)l, 16, 0, 0);
}

__device__ __forceinline__ unsigned short f2b(float x) {  // RNE fp32->bf16
  unsigned int u = __float_as_uint(x);
  u += 0x7fffu + ((u >> 16) & 1u);
  return (unsigned short)(u >> 16);
}

// ---------------- fp32 -> bf16 converts (fused) ----------------
__global__ void cvt3_kernel(const float* __restrict__ a, const float* __restrict__ b,
                            const float* __restrict__ c, unsigned short* __restrict__ out,
                            int n4) {
  const float* in = blockIdx.y == 0 ? a : blockIdx.y == 1 ? b : c;
  unsigned short* o = out + (size_t)blockIdx.y * (size_t)n4 * 4;
  int i = blockIdx.x * blockDim.x + threadIdx.x;
  if (i >= n4) return;
  float4 v = ((const float4*)in)[i];
  ushort4 r;
  r.x = f2b(v.x); r.y = f2b(v.y); r.z = f2b(v.z); r.w = f2b(v.w);
  ((ushort4*)o)[i] = r;
}

__global__ void cvt4_kernel(const float* __restrict__ a, const float* __restrict__ b,
                            const float* __restrict__ c, const float* __restrict__ d,
                            unsigned short* __restrict__ out, int n4) {
  const float* in = blockIdx.y == 0 ? a : blockIdx.y == 1 ? b : blockIdx.y == 2 ? c : d;
  unsigned short* o = out + (size_t)blockIdx.y * (size_t)n4 * 4;
  int i = blockIdx.x * blockDim.x + threadIdx.x;
  if (i >= n4) return;
  float4 v = ((const float4*)in)[i];
  ushort4 r;
  r.x = f2b(v.x); r.y = f2b(v.y); r.z = f2b(v.z); r.w = f2b(v.w);
  ((ushort4*)o)[i] = r;
}

// ---------------- GEMM body: Y[M,N] = A[M,K] * W[N,K]^T + bias ----------------
// 128x64 tile, BK=32, 4 waves, each wave 32x64 (2x4 fragments of 16x16x32).
// LDS chunk-XOR swizzle: logical 16B-chunk u of row r stored at chunk u^(r&3).
template <int EPI>
__device__ __forceinline__ void gemm_body(const unsigned short* __restrict__ A,
                                          const unsigned short* __restrict__ B,
                                          const float* __restrict__ bias,
                                          unsigned short* __restrict__ outb,
                                          float* __restrict__ outf, int bx, int M,
                                          int N, int K) {
  __shared__ __attribute__((aligned(16))) unsigned short sA[128 * 32];
  __shared__ __attribute__((aligned(16))) unsigned short sB[64 * 32];

  const int tid = threadIdx.x;
  const int w = tid >> 6, l = tid & 63;
  const int nTN = N >> 6;
  const int bm = bx / nTN, bn = bx % nTN;
  const int rowBase = bm << 7, colBase = bn << 6;
  const int g = l >> 4, c16 = l & 15;

  f32x4 acc[2][4];
#pragma unroll
  for (int i = 0; i < 2; i++)
#pragma unroll
    for (int j = 0; j < 4; j++) acc[i][j] = f4zero();

  const int rloc = l >> 2;               // 16 rows per gload (64B rows)
  const int uch = (l & 3) ^ (rloc & 3);  // pre-swizzled source chunk

  for (int kk = 0; kk < K; kk += 32) {
    __syncthreads();
    gload_lds16(A + (size_t)(rowBase + w * 16 + rloc) * K + kk + uch * 8,
                &sA[(w * 16) * 32]);
    gload_lds16(A + (size_t)(rowBase + 64 + w * 16 + rloc) * K + kk + uch * 8,
                &sA[(64 + w * 16) * 32]);
    gload_lds16(B + (size_t)(colBase + w * 16 + rloc) * K + kk + uch * 8,
                &sB[(w * 16) * 32]);
    __syncthreads();

    bf16x8 af[2], bfr[4];
#pragma unroll
    for (int mt = 0; mt < 2; mt++) {
      const int r = w * 32 + mt * 16 + c16;
      af[mt] = *(const bf16x8*)&sA[r * 32 + (g ^ (r & 3)) * 8];
    }
#pragma unroll
    for (int nt = 0; nt < 4; nt++) {
      const int r = nt * 16 + c16;
      bfr[nt] = *(const bf16x8*)&sB[r * 32 + (g ^ (r & 3)) * 8];
    }
#pragma unroll
    for (int mt = 0; mt < 2; mt++)
#pragma unroll
      for (int nt = 0; nt < 4; nt++)
        acc[mt][nt] = mfma_bf16(af[mt], bfr[nt], acc[mt][nt]);
  }

  // epilogue: C/D layout row = g*4+i, col = c16
#pragma unroll
  for (int mt = 0; mt < 2; mt++)
#pragma unroll
    for (int nt = 0; nt < 4; nt++) {
      const int col = colBase + nt * 16 + c16;
      const float bv = bias[col];
#pragma unroll
      for (int i = 0; i < 4; i++) {
        const int row = rowBase + w * 32 + mt * 16 + g * 4 + i;
        const float v = acc[mt][nt][i] + bv;
        if (EPI == 0)
          outb[(size_t)row * N + col] = f2b(v);
        else
          outf[(size_t)row * N + col] = v;
      }
    }
}

// batched Q/K/V projections: grid = 3 * 512 blocks
__global__ __launch_bounds__(256, 4) void gemm_qkv_kernel(
    const unsigned short* __restrict__ Abase, const unsigned short* __restrict__ Wbase,
    const float* __restrict__ bq, const float* __restrict__ bk,
    const float* __restrict__ bv, unsigned short* __restrict__ Obase) {
  const int nblk = (MROWS / 128) * (D_MODEL / 64);  // 512
  const int gid = blockIdx.x / nblk, bx = blockIdx.x % nblk;
  const unsigned short* A = Abase + (size_t)gid * ((size_t)MROWS * D_MODEL);
  const unsigned short* B = Wbase + (size_t)gid * ((size_t)D_MODEL * D_MODEL);
  const float* bias = gid == 0 ? bq : gid == 1 ? bk : bv;
  unsigned short* out = Obase + (size_t)gid * ((size_t)MROWS * D_MODEL);
  gemm_body<0>(A, B, bias, out, nullptr, bx, MROWS, D_MODEL, D_MODEL);
}

__global__ __launch_bounds__(256, 4) void gemm_out_kernel(
    const unsigned short* __restrict__ A, const unsigned short* __restrict__ B,
    const float* __restrict__ bias, float* __restrict__ out) {
  gemm_body<1>(A, B, bias, nullptr, out, blockIdx.x, MROWS, D_MODEL, D_MODEL);
}

// ---------------- V transpose: Vh[B,S,D] -> Vt[(b*16+h)*64+d][S] ----------
__global__ void transpose_v_kernel(const unsigned short* __restrict__ Vh,
                                   unsigned short* __restrict__ Vt) {
  const int t = threadIdx.x;
  const int d = t & 63, grp = t >> 6;
  const int s0 = blockIdx.x * 64 + grp * 16;
  const int bh = blockIdx.y;
  const int b = bh >> 4, h = bh & 15;
  unsigned short vals[16];
#pragma unroll
  for (int j = 0; j < 16; j++)
    vals[j] = Vh[(size_t)(b * SEQ + s0 + j) * D_MODEL + h * DK + d];
  unsigned short* dst = &Vt[(size_t)(bh * DK + d) * SEQ + s0];
  ((uint4*)dst)[0] = ((uint4*)vals)[0];
  ((uint4*)dst)[1] = ((uint4*)vals)[1];
}

// ---------------- flash attention ----------------
// grid (32, 32): x = 64-row q block, y = (b*16+h). 4 waves x 16 q-rows each.
// KVB=64 double-buffered (one barrier/iter). Swapped QK^T: st = mfma(K,Q) ->
// S^T[key][q] with q = c16 lane-local; softmax reduce = in-lane + 2 shfl_xor.
// P redistributed to PV A-frags fully in-register (shfl_xor 32/16 + cndmask).
__global__ __launch_bounds__(256, 4) void attn_kernel(
    const unsigned short* __restrict__ Qh, const unsigned short* __restrict__ Kh,
    const unsigned short* __restrict__ Vt, unsigned short* __restrict__ Xh) {
  __shared__ __attribute__((aligned(16))) unsigned short sK[2][KVB * 64];  // [key][d]
  __shared__ __attribute__((aligned(16))) unsigned short sV[2][64 * KVB];  // [d][key]

  const int tid = threadIdx.x, w = tid >> 6, l = tid & 63;
  const int bh = blockIdx.y, b = bh >> 4, h = bh & 15;
  const int q0 = blockIdx.x * 64 + w * 16;
  const int g = l >> 4, c16 = l & 15;

  // hoist Q B-frags: lane holds Q[q=c16][d = f*32 + g*8 + j]
  bf16x8 qf[2];
#pragma unroll
  for (int f = 0; f < 2; ++f)
    qf[f] = *(const bf16x8*)&Qh[(size_t)(b * SEQ + q0 + c16) * D_MODEL + h * DK +
                                f * 32 + g * 8];

  f32x4 acc[4];
#pragma unroll
  for (int dt = 0; dt < 4; ++dt) acc[dt] = f4zero();
  float mrun = -1e30f, lrun = 0.f;

  const int srow = l >> 3, sch = (l & 7) ^ (srow & 7);  // 8 rows/gload (128B rows)

  auto STAGE = [&](int pbuf, int kv0) {
#pragma unroll
    for (int hh = 0; hh < 2; ++hh) {
      const int r0 = w * 16 + hh * 8;
      gload_lds16(
          Kh + (size_t)(b * SEQ + kv0 + r0 + srow) * D_MODEL + h * DK + sch * 8,
          &sK[pbuf][r0 * 64]);
      gload_lds16(Vt + (size_t)(bh * DK + r0 + srow) * SEQ + kv0 + sch * 8,
                  &sV[pbuf][r0 * 64]);
    }
  };

  STAGE(0, 0);
  __syncthreads();  // drains vmcnt before barrier (compiler semantics)
  int pb = 0;

  for (int it = 0; it < NIT; ++it) {
    if (it + 1 < NIT) STAGE(pb ^ 1, (it + 1) * KVB);

    // S^T = K * Q^T  (4 key-tiles of 16)
    f32x4 st[4];
#pragma unroll
    for (int kt = 0; kt < 4; ++kt) {
      f32x4 s = f4zero();
#pragma unroll
      for (int f = 0; f < 2; ++f) {
        const int key = kt * 16 + c16;
        const int ch = (f * 4 + g) ^ (key & 7);
        bf16x8 kf = *(const bf16x8*)&sK[pb][key * 64 + ch * 8];
        s = mfma_bf16(kf, qf[f], s);
      }
      st[kt] = s;
    }

    // online softmax: lane owns q=c16; keys in-lane(16) x g-groups(4)
    float smax = st[0][0];
#pragma unroll
    for (int kt = 0; kt < 4; ++kt)
#pragma unroll
      for (int i = 0; i < 4; ++i) smax = fmaxf(smax, st[kt][i]);
    smax = fmaxf(smax, __shfl_xor(smax, 16));
    smax = fmaxf(smax, __shfl_xor(smax, 32));
    const float mx = smax * 0.125f;
    if (!__all(mx <= mrun + 8.0f)) {  // defer-max (T13)
      const float mnew = fmaxf(mrun, mx);
      const float alpha = __expf(mrun - mnew);
      lrun *= alpha;
      mrun = mnew;
#pragma unroll
      for (int i = 0; i < 4; ++i) {
        const float av = __shfl(alpha, g * 4 + i);
#pragma unroll
        for (int dt = 0; dt < 4; ++dt) acc[dt][i] *= av;
      }
    }

    float ps = 0.f;
    unsigned int Qpk[4][2];
#pragma unroll
    for (int kt = 0; kt < 4; ++kt) {
      float pv[4];
#pragma unroll
      for (int i = 0; i < 4; ++i) {
        pv[i] = __expf(fmaf(st[kt][i], 0.125f, -mrun));
        ps += pv[i];
      }
#pragma unroll
      for (int hh = 0; hh < 2; ++hh) {
        bf16x2 t2;
        t2.x = (__bf16)pv[hh * 2];
        t2.y = (__bf16)pv[hh * 2 + 1];
        Qpk[kt][hh] = __builtin_bit_cast(unsigned int, t2);
      }
    }
    ps += __shfl_xor(ps, 16);
    ps += __shfl_xor(ps, 32);
    lrun += ps;

    // redistribute P C-frags -> PV A-frags, in-register.
    // target lane (g,c16) j-th key = g*8+j; source = lane (g',c16) reg (kt,i)
    // with kt = 2ks + (g>>1), g' = (g&1)*2 + (j>>2), i = j&3.
#pragma unroll
    for (int ks = 0; ks < 2; ++ks) {
      unsigned int pw[4];
#pragma unroll
      for (int hh = 0; hh < 2; ++hh) {
        const unsigned int a = Qpk[2 * ks][hh], bb = Qpk[2 * ks + 1][hh];
        const unsigned int as = __shfl_xor((int)a, 32);
        const unsigned int bs = __shfl_xor((int)bb, 32);
        const unsigned int r0 = (l >= 32) ? bs : a;   // kt-select low/high half
        const unsigned int r1 = (l >= 32) ? bb : as;
        const unsigned int t0 = __shfl_xor((int)r0, 16);
        const unsigned int t1 = __shfl_xor((int)r1, 16);
        pw[hh] = (g & 1) ? t1 : r0;      // keys +0..3
        pw[2 + hh] = (g & 1) ? r1 : t0;  // keys +4..7
      }
      u32x4 pv4 = {pw[0], pw[1], pw[2], pw[3]};
      const bf16x8 pfrag = __builtin_bit_cast(bf16x8, pv4);
#pragma unroll
      for (int dt = 0; dt < 4; ++dt) {
        const int d = dt * 16 + c16;
        const int ch = (ks * 4 + g) ^ (d & 7);
        bf16x8 vfrag = *(const bf16x8*)&sV[pb][d * 64 + ch * 8];
        acc[dt] = mfma_bf16(pfrag, vfrag, acc[dt]);
      }
    }

    __syncthreads();  // staged next tile ready; buf pb free for overwrite
    pb ^= 1;
  }

  // finalize: divide by l; lane holds O[q=g*4+i][d=dt*16+c16]
  float linv[4];
#pragma unroll
  for (int i = 0; i < 4; ++i) linv[i] = 1.f / __shfl(lrun, g * 4 + i);
#pragma unroll
  for (int dt = 0; dt < 4; ++dt)
#pragma unroll
    for (int i = 0; i < 4; ++i) {
      const int row = b * SEQ + q0 + g * 4 + i;
      const int col = h * DK + dt * 16 + c16;
      Xh[(size_t)row * D_MODEL + col] = f2b(acc[dt][i] * linv[i]);
    }
}

// ---------------- host ----------------
extern "C" void kernel_launch(void* const* d_in, const int* in_sizes, int n_in,
                              void* d_out, int out_size, void* d_ws, size_t ws_size,
                              hipStream_t stream) {
  (void)in_sizes; (void)n_in; (void)out_size; (void)ws_size;
  const float* q = (const float*)d_in[0];
  const float* k = (const float*)d_in[1];
  const float* v = (const float*)d_in[2];
  const float* w_q = (const float*)d_in[3];
  const float* b_q = (const float*)d_in[4];
  const float* w_k = (const float*)d_in[5];
  const float* b_k = (const float*)d_in[6];
  const float* w_v = (const float*)d_in[7];
  const float* b_v = (const float*)d_in[8];
  const float* w_o = (const float*)d_in[9];
  const float* b_o = (const float*)d_in[10];

  const size_t SZ_ACT = (size_t)MROWS * D_MODEL;  // elements
  const size_t SZ_W = (size_t)D_MODEL * D_MODEL;
  char* ws = (char*)d_ws;
  // byte layout (SZ = SZ_ACT bytes*2 per buffer):
  // [0,6SZ):   q,k,v bf16 inputs (contig)  -- dead after projections
  //            [0,2SZ) reused as Xh ; [2SZ,4SZ) reused as Vt
  // [6,12SZ):  Q,K,V projections (contig)
  // [12SZ..):  wq,wk,wv,wo bf16 (contig)
  unsigned short* qb = (unsigned short*)(ws);
  unsigned short* Xh = (unsigned short*)(ws);
  unsigned short* Vt = (unsigned short*)(ws + 2 * SZ_ACT);
  unsigned short* Qproj = (unsigned short*)(ws + 6 * SZ_ACT);
  unsigned short* Vh = (unsigned short*)(ws + 10 * SZ_ACT);
  unsigned short* wqb = (unsigned short*)(ws + 12 * SZ_ACT);
  unsigned short* wob = (unsigned short*)(ws + 12 * SZ_ACT + 6 * SZ_W);

  const int actN4 = (int)(SZ_ACT / 4), wN4 = (int)(SZ_W / 4);
  cvt3_kernel<<<dim3(actN4 / 256, 3), 256, 0, stream>>>(q, k, v, qb, actN4);
  cvt4_kernel<<<dim3(wN4 / 256, 4), 256, 0, stream>>>(w_q, w_k, w_v, w_o, wqb, wN4);

  gemm_qkv_kernel<<<3 * 512, 256, 0, stream>>>(qb, wqb, b_q, b_k, b_v, Qproj);

  transpose_v_kernel<<<dim3(SEQ / 64, BATCH * NHEAD), 256, 0, stream>>>(Vh, Vt);

  // Q at Qproj, K at Qproj + SZ_ACT (elements), V consumed via Vt
  attn_kernel<<<dim3(SEQ / 64, BATCH * NHEAD), 256, 0, stream>>>(
      Qproj, Qproj + SZ_ACT, Vt, Xh);

  gemm_out_kernel<<<512, 256, 0, stream>>>(Xh, wob, b_o, (float*)d_out);
}

// Round 4
// 148.822 us; speedup vs baseline: 1.6738x; 1.1202x over previous
//
#include <hip/hip_runtime.h>
#include <stdint.h>

#define D_MODEL 1024
#define NHEAD 16
#define DK 64
#define BATCH 2
#define SEQ 2048
#define MROWS (BATCH * SEQ) /* 4096 */
#define KVB 64
#define NIT (SEQ / KVB) /* 32 */

typedef __attribute__((ext_vector_type(8))) __bf16 bf16x8;
typedef __attribute__((ext_vector_type(2))) __bf16 bf16x2;
typedef __attribute__((ext_vector_type(4))) float f32x4;
typedef __attribute__((ext_vector_type(4))) unsigned int u32x4;
typedef __attribute__((ext_vector_type(2))) unsigned int u32x2;

#if defined(__has_builtin)
#if __has_builtin(__builtin_amdgcn_permlane32_swap) && \
    __has_builtin(__builtin_amdgcn_permlane16_swap)
#define HAVE_PERMLANE_SWAP 1
#endif
#endif
#ifndef HAVE_PERMLANE_SWAP
#define HAVE_PERMLANE_SWAP 0
#endif

__device__ __forceinline__ f32x4 f4zero() {
  f32x4 z = {0.f, 0.f, 0.f, 0.f};
  return z;
}

__device__ __forceinline__ f32x4 mfma_bf16(bf16x8 a, bf16x8 b, f32x4 c) {
  return __builtin_amdgcn_mfma_f32_16x16x32_bf16(a, b, c, 0, 0, 0);
}

// async global->LDS, 16B per lane; LDS dest = wave-uniform base + lane*16
__device__ __forceinline__ void gload_lds16(const void* g, void* l) {
  __builtin_amdgcn_global_load_lds(
      (const __attribute__((address_space(1))) unsigned int*)g,
      (__attribute__((address_space(3))) unsigned int*)l, 16, 0, 0);
}

__device__ __forceinline__ unsigned short f2b(float x) {  // RNE fp32->bf16
  unsigned int u = __float_as_uint(x);
  u += 0x7fffu + ((u >> 16) & 1u);
  return (unsigned short)(u >> 16);
}

#if HAVE_PERMLANE_SWAP
__device__ __forceinline__ u32x2 pl32(unsigned int a, unsigned int b) {
  return __builtin_amdgcn_permlane32_swap(a, b, false, false);
}
__device__ __forceinline__ u32x2 pl16(unsigned int a, unsigned int b) {
  return __builtin_amdgcn_permlane16_swap(a, b, false, false);
}
// butterfly reduce over lane-xor 16 and 32 via self-swap pairs (VALU only)
__device__ __forceinline__ float redmax_hi(float x) {
  u32x2 r = pl16(__float_as_uint(x), __float_as_uint(x));
  x = fmaxf(__uint_as_float(r.x), __uint_as_float(r.y));
  u32x2 r2 = pl32(__float_as_uint(x), __float_as_uint(x));
  return fmaxf(__uint_as_float(r2.x), __uint_as_float(r2.y));
}
__device__ __forceinline__ float redsum_hi(float x) {
  u32x2 r = pl16(__float_as_uint(x), __float_as_uint(x));
  x = __uint_as_float(r.x) + __uint_as_float(r.y);
  u32x2 r2 = pl32(__float_as_uint(x), __float_as_uint(x));
  return __uint_as_float(r2.x) + __uint_as_float(r2.y);
}
#else
__device__ __forceinline__ float redmax_hi(float x) {
  x = fmaxf(x, __shfl_xor(x, 16));
  return fmaxf(x, __shfl_xor(x, 32));
}
__device__ __forceinline__ float redsum_hi(float x) {
  x += __shfl_xor(x, 16);
  return x + __shfl_xor(x, 32);
}
#endif

// ---------------- fp32 -> bf16 converts (fused) ----------------
__global__ void cvt3_kernel(const float* __restrict__ a, const float* __restrict__ b,
                            const float* __restrict__ c, unsigned short* __restrict__ out,
                            int n4) {
  const float* in = blockIdx.y == 0 ? a : blockIdx.y == 1 ? b : c;
  unsigned short* o = out + (size_t)blockIdx.y * (size_t)n4 * 4;
  int i = blockIdx.x * blockDim.x + threadIdx.x;
  if (i >= n4) return;
  float4 v = ((const float4*)in)[i];
  ushort4 r;
  r.x = f2b(v.x); r.y = f2b(v.y); r.z = f2b(v.z); r.w = f2b(v.w);
  ((ushort4*)o)[i] = r;
}

__global__ void cvt4_kernel(const float* __restrict__ a, const float* __restrict__ b,
                            const float* __restrict__ c, const float* __restrict__ d,
                            unsigned short* __restrict__ out, int n4) {
  const float* in = blockIdx.y == 0 ? a : blockIdx.y == 1 ? b : blockIdx.y == 2 ? c : d;
  unsigned short* o = out + (size_t)blockIdx.y * (size_t)n4 * 4;
  int i = blockIdx.x * blockDim.x + threadIdx.x;
  if (i >= n4) return;
  float4 v = ((const float4*)in)[i];
  ushort4 r;
  r.x = f2b(v.x); r.y = f2b(v.y); r.z = f2b(v.z); r.w = f2b(v.w);
  ((ushort4*)o)[i] = r;
}

// -------- GEMM 128x128 (m97-class): Y[M,N] = A[M,K]*W[N,K]^T + bias --------
// BK=32, 4 waves, each wave 64x64 (4x4 frags of 16x16x32).
// LDS chunk-XOR swizzle: logical 16B-chunk u of row r stored at chunk u^(r&3).
template <int EPI>
__device__ __forceinline__ void gemm_body128(const unsigned short* __restrict__ A,
                                             const unsigned short* __restrict__ B,
                                             const float* __restrict__ bias,
                                             unsigned short* __restrict__ outb,
                                             float* __restrict__ outf, int bx,
                                             int M, int N, int K) {
  __shared__ __attribute__((aligned(16))) unsigned short sA[128 * 32];
  __shared__ __attribute__((aligned(16))) unsigned short sB[128 * 32];

  const int tid = threadIdx.x;
  const int w = tid >> 6, l = tid & 63;
  const int nTN = N >> 7;
  const int bm = bx / nTN, bn = bx % nTN;
  const int rowBase = bm << 7, colBase = bn << 7;
  const int wm = w >> 1, wn = w & 1;
  const int g = l >> 4, c16 = l & 15;

  f32x4 acc[4][4];
#pragma unroll
  for (int i = 0; i < 4; i++)
#pragma unroll
    for (int j = 0; j < 4; j++) acc[i][j] = f4zero();

  const int rloc = l >> 2;               // 16 rows per gload (64B rows)
  const int uch = (l & 3) ^ (rloc & 3);  // pre-swizzled source chunk

  for (int kk = 0; kk < K; kk += 32) {
    __syncthreads();
#pragma unroll
    for (int h = 0; h < 2; h++) {
      const int r0 = w * 16 + h * 64;
      gload_lds16(A + (size_t)(rowBase + r0 + rloc) * K + kk + uch * 8,
                  &sA[r0 * 32]);
      gload_lds16(B + (size_t)(colBase + r0 + rloc) * K + kk + uch * 8,
                  &sB[r0 * 32]);
    }
    __syncthreads();

    bf16x8 af[4], bfr[4];
#pragma unroll
    for (int mt = 0; mt < 4; mt++) {
      const int r = wm * 64 + mt * 16 + c16;
      af[mt] = *(const bf16x8*)&sA[r * 32 + (g ^ (r & 3)) * 8];
    }
#pragma unroll
    for (int nt = 0; nt < 4; nt++) {
      const int r = wn * 64 + nt * 16 + c16;
      bfr[nt] = *(const bf16x8*)&sB[r * 32 + (g ^ (r & 3)) * 8];
    }
#pragma unroll
    for (int mt = 0; mt < 4; mt++)
#pragma unroll
      for (int nt = 0; nt < 4; nt++)
        acc[mt][nt] = mfma_bf16(af[mt], bfr[nt], acc[mt][nt]);
  }

  // epilogue: C/D layout row = g*4+i, col = c16
#pragma unroll
  for (int mt = 0; mt < 4; mt++)
#pragma unroll
    for (int nt = 0; nt < 4; nt++) {
      const int col = colBase + wn * 64 + nt * 16 + c16;
      const float bv = bias[col];
#pragma unroll
      for (int i = 0; i < 4; i++) {
        const int row = rowBase + wm * 64 + mt * 16 + g * 4 + i;
        const float v = acc[mt][nt][i] + bv;
        if (EPI == 0)
          outb[(size_t)row * N + col] = f2b(v);
        else
          outf[(size_t)row * N + col] = v;
      }
    }
}

// -------- GEMM 128x64 (for the 1024-col output projection: 512 blocks) -----
template <int EPI>
__device__ __forceinline__ void gemm_body64(const unsigned short* __restrict__ A,
                                            const unsigned short* __restrict__ B,
                                            const float* __restrict__ bias,
                                            unsigned short* __restrict__ outb,
                                            float* __restrict__ outf, int bx,
                                            int M, int N, int K) {
  __shared__ __attribute__((aligned(16))) unsigned short sA[128 * 32];
  __shared__ __attribute__((aligned(16))) unsigned short sB[64 * 32];

  const int tid = threadIdx.x;
  const int w = tid >> 6, l = tid & 63;
  const int nTN = N >> 6;
  const int bm = bx / nTN, bn = bx % nTN;
  const int rowBase = bm << 7, colBase = bn << 6;
  const int g = l >> 4, c16 = l & 15;

  f32x4 acc[2][4];
#pragma unroll
  for (int i = 0; i < 2; i++)
#pragma unroll
    for (int j = 0; j < 4; j++) acc[i][j] = f4zero();

  const int rloc = l >> 2;
  const int uch = (l & 3) ^ (rloc & 3);

  for (int kk = 0; kk < K; kk += 32) {
    __syncthreads();
    gload_lds16(A + (size_t)(rowBase + w * 16 + rloc) * K + kk + uch * 8,
                &sA[(w * 16) * 32]);
    gload_lds16(A + (size_t)(rowBase + 64 + w * 16 + rloc) * K + kk + uch * 8,
                &sA[(64 + w * 16) * 32]);
    gload_lds16(B + (size_t)(colBase + w * 16 + rloc) * K + kk + uch * 8,
                &sB[(w * 16) * 32]);
    __syncthreads();

    bf16x8 af[2], bfr[4];
#pragma unroll
    for (int mt = 0; mt < 2; mt++) {
      const int r = w * 32 + mt * 16 + c16;
      af[mt] = *(const bf16x8*)&sA[r * 32 + (g ^ (r & 3)) * 8];
    }
#pragma unroll
    for (int nt = 0; nt < 4; nt++) {
      const int r = nt * 16 + c16;
      bfr[nt] = *(const bf16x8*)&sB[r * 32 + (g ^ (r & 3)) * 8];
    }
#pragma unroll
    for (int mt = 0; mt < 2; mt++)
#pragma unroll
      for (int nt = 0; nt < 4; nt++)
        acc[mt][nt] = mfma_bf16(af[mt], bfr[nt], acc[mt][nt]);
  }

#pragma unroll
  for (int mt = 0; mt < 2; mt++)
#pragma unroll
    for (int nt = 0; nt < 4; nt++) {
      const int col = colBase + nt * 16 + c16;
      const float bv = bias[col];
#pragma unroll
      for (int i = 0; i < 4; i++) {
        const int row = rowBase + w * 32 + mt * 16 + g * 4 + i;
        const float v = acc[mt][nt][i] + bv;
        if (EPI == 0)
          outb[(size_t)row * N + col] = f2b(v);
        else
          outf[(size_t)row * N + col] = v;
      }
    }
}

// batched Q/K/V projections: grid = 3 * 256 blocks of 128x128
__global__ __launch_bounds__(256, 2) void gemm_qkv_kernel(
    const unsigned short* __restrict__ Abase, const unsigned short* __restrict__ Wbase,
    const float* __restrict__ bq, const float* __restrict__ bk,
    const float* __restrict__ bv, unsigned short* __restrict__ Obase) {
  const int nblk = (MROWS / 128) * (D_MODEL / 128);  // 256
  const int gid = blockIdx.x / nblk, bx = blockIdx.x % nblk;
  const unsigned short* A = Abase + (size_t)gid * ((size_t)MROWS * D_MODEL);
  const unsigned short* B = Wbase + (size_t)gid * ((size_t)D_MODEL * D_MODEL);
  const float* bias = gid == 0 ? bq : gid == 1 ? bk : bv;
  unsigned short* out = Obase + (size_t)gid * ((size_t)MROWS * D_MODEL);
  gemm_body128<0>(A, B, bias, out, nullptr, bx, MROWS, D_MODEL, D_MODEL);
}

__global__ __launch_bounds__(256, 4) void gemm_out_kernel(
    const unsigned short* __restrict__ A, const unsigned short* __restrict__ B,
    const float* __restrict__ bias, float* __restrict__ out) {
  gemm_body64<1>(A, B, bias, nullptr, out, blockIdx.x, MROWS, D_MODEL, D_MODEL);
}

// ---------------- V transpose: Vh[B,S,D] -> Vt[(b*16+h)*64+d][S] ----------
__global__ void transpose_v_kernel(const unsigned short* __restrict__ Vh,
                                   unsigned short* __restrict__ Vt) {
  const int t = threadIdx.x;
  const int d = t & 63, grp = t >> 6;
  const int s0 = blockIdx.x * 64 + grp * 16;
  const int bh = blockIdx.y;
  const int b = bh >> 4, h = bh & 15;
  unsigned short vals[16];
#pragma unroll
  for (int j = 0; j < 16; j++)
    vals[j] = Vh[(size_t)(b * SEQ + s0 + j) * D_MODEL + h * DK + d];
  unsigned short* dst = &Vt[(size_t)(bh * DK + d) * SEQ + s0];
  ((uint4*)dst)[0] = ((uint4*)vals)[0];
  ((uint4*)dst)[1] = ((uint4*)vals)[1];
}

// ---------------- flash attention ----------------
// grid (32, 32): x = 64-row q block, y = (b*16+h). 4 waves x 16 q-rows each.
// KVB=64 double-buffered (one barrier/iter). Swapped QK^T: st = mfma(K,Q) ->
// S^T[key][q] with q = c16 lane-local; row reduces + P-redistribution done
// entirely with v_permlane{16,32}_swap (VALU) -- no DS-pipe shuffles.
__global__ __launch_bounds__(256, 4) void attn_kernel(
    const unsigned short* __restrict__ Qh, const unsigned short* __restrict__ Kh,
    const unsigned short* __restrict__ Vt, unsigned short* __restrict__ Xh) {
  __shared__ __attribute__((aligned(16))) unsigned short sK[2][KVB * 64];  // [key][d]
  __shared__ __attribute__((aligned(16))) unsigned short sV[2][64 * KVB];  // [d][key]

  const int tid = threadIdx.x, w = tid >> 6, l = tid & 63;
  const int bh = blockIdx.y, b = bh >> 4, h = bh & 15;
  const int q0 = blockIdx.x * 64 + w * 16;
  const int g = l >> 4, c16 = l & 15;

  // hoist Q B-frags: lane holds Q[q=c16][d = f*32 + g*8 + j]
  bf16x8 qf[2];
#pragma unroll
  for (int f = 0; f < 2; ++f)
    qf[f] = *(const bf16x8*)&Qh[(size_t)(b * SEQ + q0 + c16) * D_MODEL + h * DK +
                                f * 32 + g * 8];

  f32x4 acc[4];
#pragma unroll
  for (int dt = 0; dt < 4; ++dt) acc[dt] = f4zero();
  float mrun = -1e30f, lrun = 0.f;

  const int srow = l >> 3, sch = (l & 7) ^ (srow & 7);  // 8 rows/gload (128B rows)

  auto STAGE = [&](int pbuf, int kv0) {
#pragma unroll
    for (int hh = 0; hh < 2; ++hh) {
      const int r0 = w * 16 + hh * 8;
      gload_lds16(
          Kh + (size_t)(b * SEQ + kv0 + r0 + srow) * D_MODEL + h * DK + sch * 8,
          &sK[pbuf][r0 * 64]);
      gload_lds16(Vt + (size_t)(bh * DK + r0 + srow) * SEQ + kv0 + sch * 8,
                  &sV[pbuf][r0 * 64]);
    }
  };

  STAGE(0, 0);
  __syncthreads();  // drains vmcnt before barrier (compiler semantics)
  int pb = 0;

  for (int it = 0; it < NIT; ++it) {
    if (it + 1 < NIT) STAGE(pb ^ 1, (it + 1) * KVB);

    // S^T = K * Q^T  (4 key-tiles of 16)
    f32x4 st[4];
#pragma unroll
    for (int kt = 0; kt < 4; ++kt) {
      f32x4 s = f4zero();
#pragma unroll
      for (int f = 0; f < 2; ++f) {
        const int key = kt * 16 + c16;
        const int ch = (f * 4 + g) ^ (key & 7);
        bf16x8 kf = *(const bf16x8*)&sK[pb][key * 64 + ch * 8];
        s = mfma_bf16(kf, qf[f], s);
      }
      st[kt] = s;
    }

    // online softmax: lane owns q=c16; keys in-lane(16) x g-groups(4)
    float smax = st[0][0];
#pragma unroll
    for (int kt = 0; kt < 4; ++kt)
#pragma unroll
      for (int i = 0; i < 4; ++i) smax = fmaxf(smax, st[kt][i]);
    smax = redmax_hi(smax);
    const float mx = smax * 0.125f;
    if (!__all(mx <= mrun + 8.0f)) {  // defer-max (T13)
      const float mnew = fmaxf(mrun, mx);
      const float alpha = __expf(mrun - mnew);
      lrun *= alpha;
      mrun = mnew;
#pragma unroll
      for (int i = 0; i < 4; ++i) {
        const float av = __shfl(alpha, g * 4 + i);
#pragma unroll
        for (int dt = 0; dt < 4; ++dt) acc[dt][i] *= av;
      }
    }

    float ps = 0.f;
    unsigned int Qpk[4][2];
#pragma unroll
    for (int kt = 0; kt < 4; ++kt) {
      float pv[4];
#pragma unroll
      for (int i = 0; i < 4; ++i) {
        pv[i] = __expf(fmaf(st[kt][i], 0.125f, -mrun));
        ps += pv[i];
      }
#pragma unroll
      for (int hh = 0; hh < 2; ++hh) {
        bf16x2 t2;
        t2.x = (__bf16)pv[hh * 2];
        t2.y = (__bf16)pv[hh * 2 + 1];
        Qpk[kt][hh] = __builtin_bit_cast(unsigned int, t2);
      }
    }
    ps = redsum_hi(ps);
    lrun += ps;

    // redistribute P C-frags -> PV A-frags, in-register.
    // target lane (g,c16) j-th key = g*8+j; source = lane (g',c16) reg (kt,i)
    // with kt = 2ks + (g>>1), g' = (g&1)*2 + (j>>2), i = j&3.
#pragma unroll
    for (int ks = 0; ks < 2; ++ks) {
      unsigned int pw[4];
#if HAVE_PERMLANE_SWAP
#pragma unroll
      for (int hh = 0; hh < 2; ++hh) {
        // pl32(a,b) = (r0,r1): r0 = lanes<32 ? a : b(l-32); r1 = a(l+32)/b.
        u32x2 s1 = pl32(Qpk[2 * ks][hh], Qpk[2 * ks + 1][hh]);
        // pl16(r0,r1) = (pw_lo,pw_hi): rows [r0_0,r1_0,r0_2,r1_2] / [r0_1,r1_1,r0_3,r1_3]
        u32x2 s2 = pl16(s1.x, s1.y);
        pw[hh] = s2.x;
        pw[2 + hh] = s2.y;
      }
#else
#pragma unroll
      for (int hh = 0; hh < 2; ++hh) {
        const unsigned int a = Qpk[2 * ks][hh], bb = Qpk[2 * ks + 1][hh];
        const unsigned int as = __shfl_xor((int)a, 32);
        const unsigned int bs = __shfl_xor((int)bb, 32);
        const unsigned int r0 = (l >= 32) ? bs : a;
        const unsigned int r1 = (l >= 32) ? bb : as;
        const unsigned int t0 = __shfl_xor((int)r0, 16);
        const unsigned int t1 = __shfl_xor((int)r1, 16);
        pw[hh] = (g & 1) ? t1 : r0;
        pw[2 + hh] = (g & 1) ? r1 : t0;
      }
#endif
      u32x4 pv4 = {pw[0], pw[1], pw[2], pw[3]};
      const bf16x8 pfrag = __builtin_bit_cast(bf16x8, pv4);
#pragma unroll
      for (int dt = 0; dt < 4; ++dt) {
        const int d = dt * 16 + c16;
        const int ch = (ks * 4 + g) ^ (d & 7);
        bf16x8 vfrag = *(const bf16x8*)&sV[pb][d * 64 + ch * 8];
        acc[dt] = mfma_bf16(pfrag, vfrag, acc[dt]);
      }
    }

    __syncthreads();  // staged next tile ready; buf pb free for overwrite
    pb ^= 1;
  }

  // finalize: divide by l; lane holds O[q=g*4+i][d=dt*16+c16]
  float linv[4];
#pragma unroll
  for (int i = 0; i < 4; ++i) linv[i] = 1.f / __shfl(lrun, g * 4 + i);
#pragma unroll
  for (int dt = 0; dt < 4; ++dt)
#pragma unroll
    for (int i = 0; i < 4; ++i) {
      const int row = b * SEQ + q0 + g * 4 + i;
      const int col = h * DK + dt * 16 + c16;
      Xh[(size_t)row * D_MODEL + col] = f2b(acc[dt][i] * linv[i]);
    }
}

// ---------------- host ----------------
extern "C" void kernel_launch(void* const* d_in, const int* in_sizes, int n_in,
                              void* d_out, int out_size, void* d_ws, size_t ws_size,
                              hipStream_t stream) {
  (void)in_sizes; (void)n_in; (void)out_size; (void)ws_size;
  const float* q = (const float*)d_in[0];
  const float* k = (const float*)d_in[1];
  const float* v = (const float*)d_in[2];
  const float* w_q = (const float*)d_in[3];
  const float* b_q = (const float*)d_in[4];
  const float* w_k = (const float*)d_in[5];
  const float* b_k = (const float*)d_in[6];
  const float* w_v = (const float*)d_in[7];
  const float* b_v = (const float*)d_in[8];
  const float* w_o = (const float*)d_in[9];
  const float* b_o = (const float*)d_in[10];

  const size_t SZ_ACT = (size_t)MROWS * D_MODEL;  // elements
  const size_t SZ_W = (size_t)D_MODEL * D_MODEL;
  char* ws = (char*)d_ws;
  // byte layout:
  // [0,6SZ):   q,k,v bf16 inputs (contig)  -- dead after projections
  //            [0,2SZ) reused as Xh ; [2SZ,4SZ) reused as Vt
  // [6,12SZ):  Q,K,V projections (contig)
  // [12SZ..):  wq,wk,wv,wo bf16 (contig)
  unsigned short* qb = (unsigned short*)(ws);
  unsigned short* Xh = (unsigned short*)(ws);
  unsigned short* Vt = (unsigned short*)(ws + 2 * SZ_ACT);
  unsigned short* Qproj = (unsigned short*)(ws + 6 * SZ_ACT);
  unsigned short* Vh = (unsigned short*)(ws + 10 * SZ_ACT);
  unsigned short* wqb = (unsigned short*)(ws + 12 * SZ_ACT);
  unsigned short* wob = (unsigned short*)(ws + 12 * SZ_ACT + 6 * SZ_W);

  const int actN4 = (int)(SZ_ACT / 4), wN4 = (int)(SZ_W / 4);
  cvt3_kernel<<<dim3(actN4 / 256, 3), 256, 0, stream>>>(q, k, v, qb, actN4);
  cvt4_kernel<<<dim3(wN4 / 256, 4), 256, 0, stream>>>(w_q, w_k, w_v, w_o, wqb, wN4);

  gemm_qkv_kernel<<<3 * 256, 256, 0, stream>>>(qb, wqb, b_q, b_k, b_v, Qproj);

  transpose_v_kernel<<<dim3(SEQ / 64, BATCH * NHEAD), 256, 0, stream>>>(Vh, Vt);

  // Q at Qproj, K at Qproj + SZ_ACT (elements), V consumed via Vt
  attn_kernel<<<dim3(SEQ / 64, BATCH * NHEAD), 256, 0, stream>>>(
      Qproj, Qproj + SZ_ACT, Vt, Xh);

  gemm_out_kernel<<<512, 256, 0, stream>>>(Xh, wob, b_o, (float*)d_out);
}